// Round 10
// baseline (132.410 us; speedup 1.0000x reference)
//
#include <hip/hip_runtime.h>

// Problem constants
#define B_   64
#define M_   256
#define D_   256
#define A_   18
#define E_   4
#define S_   64
#define ES_  256          // E_*S_ == M_
#define H_   512
#define K2_  (A_*D_)      // 4608

typedef _Float16 f16;
typedef _Float16 f16x4 __attribute__((ext_vector_type(4)));
typedef _Float16 f16x8 __attribute__((ext_vector_type(8)));
typedef float    f32x4 __attribute__((ext_vector_type(4)));

static __device__ __forceinline__ f16x8 cat8(f16x4 a, f16x4 b) {
  return __builtin_shufflevector(a, b, 0, 1, 2, 3, 4, 5, 6, 7);
}
static __device__ __forceinline__ f16x8 pack8(float4 u0, float4 u1) {
  f16x8 a;
  a[0] = (f16)u0.x; a[1] = (f16)u0.y; a[2] = (f16)u0.z; a[3] = (f16)u0.w;
  a[4] = (f16)u1.x; a[5] = (f16)u1.y; a[6] = (f16)u1.z; a[7] = (f16)u1.w;
  return a;
}

// ===========================================================================
// k_sched: order[rank(b)] = b, ranked by (action[b], b). 1 block, 64 threads.
// ===========================================================================
__global__ __launch_bounds__(64) void k_sched(
    const int* __restrict__ action, int* __restrict__ order)
{
  const int t = threadIdx.x;
  const int a = action[t];
  int rank = 0;
#pragma unroll 8
  for (int i = 0; i < B_; ++i) {
    const int ai = action[i];
    rank += (ai < a) || (ai == a && i < t);
  }
  order[rank] = t;
}

// ===========================================================================
// fp32 src [z][R][C] -> fp16 dst [z][C][R]  (transpose + convert) — weights
// ===========================================================================
__global__ __launch_bounds__(256) void k_tcvt(
    const float* __restrict__ src, f16* __restrict__ dst,
    int R, int C, long sbs, long dbs)
{
  __shared__ f16 T[64][68];
  const int t = threadIdx.x;
  const int rr = t >> 4, cc = (t & 15) * 4;
  const int r0 = blockIdx.y * 64, c0 = blockIdx.x * 64;
  src += (long)blockIdx.z * sbs;
  dst += (long)blockIdx.z * dbs;
#pragma unroll
  for (int p = 0; p < 4; ++p) {
    const int row = rr + p * 16;
    const float4 v = *reinterpret_cast<const float4*>(
        &src[(long)(r0 + row) * C + c0 + cc]);
    T[row][cc + 0] = (f16)v.x; T[row][cc + 1] = (f16)v.y;
    T[row][cc + 2] = (f16)v.z; T[row][cc + 3] = (f16)v.w;
  }
  __syncthreads();
#pragma unroll
  for (int p = 0; p < 4; ++p) {
    const int oc = rr + p * 16;
    f16x4 g;
#pragma unroll
    for (int i = 0; i < 4; ++i) g[i] = T[cc + i][oc];
    *reinterpret_cast<f16x4*>(&dst[(long)(c0 + oc) * R + r0 + cc]) = g;
  }
}

// obs fp32 [b][M][D] -> obsT16 [b][D][M]
__global__ __launch_bounds__(256) void k_cvt_obsT(
    const float* __restrict__ obs, f16* __restrict__ oT)
{
  __shared__ f16 T[64][68];
  const int t = threadIdx.x, rr = t >> 4, cc = (t & 15) * 4;
  const int r0 = blockIdx.y * 64, c0 = blockIdx.x * 64;
  const long bo = (long)blockIdx.z * (M_ * D_);
#pragma unroll
  for (int p = 0; p < 4; ++p) {
    const int row = rr + p * 16;
    const float4 v = *reinterpret_cast<const float4*>(
        &obs[bo + (long)(r0 + row) * D_ + c0 + cc]);
    T[row][cc + 0] = (f16)v.x; T[row][cc + 1] = (f16)v.y;
    T[row][cc + 2] = (f16)v.z; T[row][cc + 3] = (f16)v.w;
  }
  __syncthreads();
#pragma unroll
  for (int p = 0; p < 4; ++p) {
    const int oc = rr + p * 16;
    f16x4 g;
#pragma unroll
    for (int i = 0; i < 4; ++i) g[i] = T[cc + i][oc];
    *reinterpret_cast<f16x4*>(&oT[bo + (long)(c0 + oc) * M_ + r0 + cc]) = g;
  }
}

// ===========================================================================
// k_logits_f: per 64x64 tile of logits[b] = obs_fp32[b] @ phiT^T:
//   exp16 [b][m][es], expT16[b][es][m], rowpart/colpart partial sums.
// grid (4 es, 4 m, 64 b), 256 threads
// ===========================================================================
__global__ __launch_bounds__(256) void k_logits_f(
    const float* __restrict__ obs, const f16* __restrict__ phiT,
    f16* __restrict__ exp16, f16* __restrict__ expT16,
    float* __restrict__ rowpart, float* __restrict__ colpart)
{
  __shared__ f16 T[64][68];
  const int t = threadIdx.x;
  const int es0 = blockIdx.x * 64, m0g = blockIdx.y * 64;
  const int bz = blockIdx.z;
  const long bo = (long)bz * (M_ * D_);
  const long bb = (long)bz * (M_ * ES_);

  const int w = t >> 6, lane = t & 63;
  const int wr = w >> 1, wc = w & 1;
  const int lr = lane & 15, lk = (lane >> 4) * 8;
  const int orow = (lane >> 4) * 4;

  f32x4 acc[2][2] = {};
  const float* Ap = obs + bo + (long)(m0g + wr * 32 + lr) * D_ + lk;
  const f16*   Bp = phiT + (long)(es0 + wc * 32 + lr) * D_ + lk;
#pragma unroll
  for (int k0 = 0; k0 < D_; k0 += 32) {
    const float4 u00 = *reinterpret_cast<const float4*>(Ap + k0);
    const float4 u01 = *reinterpret_cast<const float4*>(Ap + k0 + 4);
    const float4 u10 = *reinterpret_cast<const float4*>(Ap + 16 * D_ + k0);
    const float4 u11 = *reinterpret_cast<const float4*>(Ap + 16 * D_ + k0 + 4);
    const f16x8 a0 = pack8(u00, u01);
    const f16x8 a1 = pack8(u10, u11);
    const f16x8 b0 = *reinterpret_cast<const f16x8*>(Bp + k0);
    const f16x8 b1 = *reinterpret_cast<const f16x8*>(Bp + 16 * D_ + k0);
    acc[0][0] = __builtin_amdgcn_mfma_f32_16x16x32_f16(a0, b0, acc[0][0], 0, 0, 0);
    acc[0][1] = __builtin_amdgcn_mfma_f32_16x16x32_f16(a0, b1, acc[0][1], 0, 0, 0);
    acc[1][0] = __builtin_amdgcn_mfma_f32_16x16x32_f16(a1, b0, acc[1][0], 0, 0, 0);
    acc[1][1] = __builtin_amdgcn_mfma_f32_16x16x32_f16(a1, b1, acc[1][1], 0, 0, 0);
  }
#pragma unroll
  for (int fi = 0; fi < 2; ++fi)
#pragma unroll
    for (int fj = 0; fj < 2; ++fj) {
      const int gm = wr * 32 + fi * 16 + orow;
      const int gn = wc * 32 + fj * 16 + lr;
#pragma unroll
      for (int r = 0; r < 4; ++r)
        T[gm + r][gn] = (f16)__expf(acc[fi][fj][r]);
    }
  __syncthreads();

  {  // exp16 [m][es]
    const int row = t >> 2, q = t & 3;
    f16x4 p0 = *reinterpret_cast<const f16x4*>(&T[row][q * 16 + 0]);
    f16x4 p1 = *reinterpret_cast<const f16x4*>(&T[row][q * 16 + 4]);
    f16x4 p2 = *reinterpret_cast<const f16x4*>(&T[row][q * 16 + 8]);
    f16x4 p3 = *reinterpret_cast<const f16x4*>(&T[row][q * 16 + 12]);
    f16* dst = exp16 + bb + (long)(m0g + row) * ES_ + es0 + q * 16;
    *reinterpret_cast<f16x8*>(dst)     = cat8(p0, p1);
    *reinterpret_cast<f16x8*>(dst + 8) = cat8(p2, p3);
  }
  {  // expT16 [es][m]
    const int er = t >> 2, q = t & 3;
    f16x4 g[4];
#pragma unroll
    for (int j = 0; j < 4; ++j)
#pragma unroll
      for (int i = 0; i < 4; ++i)
        g[j][i] = T[q * 16 + j * 4 + i][er];
    f16* dst = expT16 + bb + (long)(es0 + er) * M_ + m0g + q * 16;
    *reinterpret_cast<f16x8*>(dst)     = cat8(g[0], g[1]);
    *reinterpret_cast<f16x8*>(dst + 8) = cat8(g[2], g[3]);
  }
  if (t < 64) {
    float s = 0.f;
#pragma unroll
    for (int i = 0; i < 16; ++i) {
      const f16x4 v = *reinterpret_cast<const f16x4*>(&T[t][i * 4]);
      s += (float)v[0] + (float)v[1] + (float)v[2] + (float)v[3];
    }
    rowpart[((long)bz * 256 + m0g + t) * 4 + blockIdx.x] = s;
  } else if (t < 128) {
    const int es = t - 64;
    float s = 0.f;
#pragma unroll
    for (int i = 0; i < 64; ++i) s += (float)T[i][es];
    colpart[((long)bz * 256 + es0 + es) * 4 + blockIdx.y] = s;
  }
}

// ===========================================================================
// k_slots_s: slots16[b][es][d] = (1/colsum[es]) * expT16[b] @ obsT16[b]^T
// grid (4 d, 4 es, 64 b), 256 threads
// ===========================================================================
__global__ __launch_bounds__(256) void k_slots_s(
    const f16* __restrict__ expT16, const f16* __restrict__ obsT16,
    const float* __restrict__ colpart, f16* __restrict__ slots16)
{
  const int t = threadIdx.x;
  const int w = t >> 6, lane = t & 63;
  const int wr = w >> 1, wc = w & 1;
  const int m0 = blockIdx.y * 64 + wr * 32;
  const int n0 = blockIdx.x * 64 + wc * 32;
  const int lr = lane & 15, lk = (lane >> 4) * 8;
  const long b = blockIdx.z;

  f32x4 acc[2][2] = {};
  const f16* Ap = expT16 + b * (ES_ * M_) + (long)(m0 + lr) * M_ + lk;
  const f16* Bp = obsT16 + b * (D_ * M_) + (long)(n0 + lr) * M_ + lk;
#pragma unroll
  for (int k0 = 0; k0 < M_; k0 += 32) {
    const f16x8 a0 = *reinterpret_cast<const f16x8*>(Ap + k0);
    const f16x8 a1 = *reinterpret_cast<const f16x8*>(Ap + 16 * M_ + k0);
    const f16x8 b0 = *reinterpret_cast<const f16x8*>(Bp + k0);
    const f16x8 b1 = *reinterpret_cast<const f16x8*>(Bp + 16 * M_ + k0);
    acc[0][0] = __builtin_amdgcn_mfma_f32_16x16x32_f16(a0, b0, acc[0][0], 0, 0, 0);
    acc[0][1] = __builtin_amdgcn_mfma_f32_16x16x32_f16(a0, b1, acc[0][1], 0, 0, 0);
    acc[1][0] = __builtin_amdgcn_mfma_f32_16x16x32_f16(a1, b0, acc[1][0], 0, 0, 0);
    acc[1][1] = __builtin_amdgcn_mfma_f32_16x16x32_f16(a1, b1, acc[1][1], 0, 0, 0);
  }

  const int orow = (lane >> 4) * 4;
  f16* C = slots16 + b * (ES_ * D_);
#pragma unroll
  for (int fi = 0; fi < 2; ++fi) {
    float inv[4];
#pragma unroll
    for (int r = 0; r < 4; ++r) {
      const int gm = m0 + fi * 16 + orow + r;
      const float4 cp = *reinterpret_cast<const float4*>(&colpart[((long)b * 256 + gm) * 4]);
      inv[r] = 1.0f / (cp.x + cp.y + cp.z + cp.w);
    }
#pragma unroll
    for (int fj = 0; fj < 2; ++fj) {
      const int gm = m0 + fi * 16 + orow;
      const int gn = n0 + fj * 16 + lr;
#pragma unroll
      for (int r = 0; r < 4; ++r)
        C[(long)(gm + r) * D_ + gn] = (f16)(acc[fi][fj][r] * inv[r]);
    }
  }
}

// ===========================================================================
// k_out_s: out[b][m][d] (fp32) = (1/rowsum[m]) * exp16[b] @ yT16[b]^T
// grid (4 d, 4 m, 64 b), 256 threads
// ===========================================================================
__global__ __launch_bounds__(256) void k_out_s(
    const f16* __restrict__ exp16, const f16* __restrict__ yT16,
    const float* __restrict__ rowpart, float* __restrict__ out)
{
  const int t = threadIdx.x;
  const int w = t >> 6, lane = t & 63;
  const int wr = w >> 1, wc = w & 1;
  const int m0 = blockIdx.y * 64 + wr * 32;
  const int n0 = blockIdx.x * 64 + wc * 32;
  const int lr = lane & 15, lk = (lane >> 4) * 8;
  const long b = blockIdx.z;

  f32x4 acc[2][2] = {};
  const f16* Ap = exp16 + b * (M_ * ES_) + (long)(m0 + lr) * ES_ + lk;
  const f16* Bp = yT16 + b * (D_ * ES_) + (long)(n0 + lr) * ES_ + lk;
#pragma unroll
  for (int k0 = 0; k0 < ES_; k0 += 32) {
    const f16x8 a0 = *reinterpret_cast<const f16x8*>(Ap + k0);
    const f16x8 a1 = *reinterpret_cast<const f16x8*>(Ap + 16 * ES_ + k0);
    const f16x8 b0 = *reinterpret_cast<const f16x8*>(Bp + k0);
    const f16x8 b1 = *reinterpret_cast<const f16x8*>(Bp + 16 * ES_ + k0);
    acc[0][0] = __builtin_amdgcn_mfma_f32_16x16x32_f16(a0, b0, acc[0][0], 0, 0, 0);
    acc[0][1] = __builtin_amdgcn_mfma_f32_16x16x32_f16(a0, b1, acc[0][1], 0, 0, 0);
    acc[1][0] = __builtin_amdgcn_mfma_f32_16x16x32_f16(a1, b0, acc[1][0], 0, 0, 0);
    acc[1][1] = __builtin_amdgcn_mfma_f32_16x16x32_f16(a1, b1, acc[1][1], 0, 0, 0);
  }

  const int orow = (lane >> 4) * 4;
  float* C = out + b * (M_ * D_);
#pragma unroll
  for (int fi = 0; fi < 2; ++fi) {
    float inv[4];
#pragma unroll
    for (int r = 0; r < 4; ++r) {
      const int gm = m0 + fi * 16 + orow + r;
      const float4 rp = *reinterpret_cast<const float4*>(&rowpart[((long)b * 256 + gm) * 4]);
      inv[r] = 1.0f / (rp.x + rp.y + rp.z + rp.w);
    }
#pragma unroll
    for (int fj = 0; fj < 2; ++fj) {
      const int gm = m0 + fi * 16 + orow;
      const int gn = n0 + fj * 16 + lr;
#pragma unroll
      for (int r = 0; r < 4; ++r)
        C[(long)(gm + r) * D_ + gn] = acc[fi][fj][r] * inv[r];
    }
  }
}

// ===========================================================================
// k_hy4: fused h->y per (b,e,half-of-s). 512 blocks, 512 threads.
// Block decode: XCD-chunk swizzle -> {e major, action-sorted b, half minor}:
// blocks sharing the (e, action) w2T slice (256 KB f16, L2-fit) run
// adjacently on the SAME XCD. GEMM2 reads w2T f16 K-contiguous (coalesced
// 16B/lane) with depth-2 register prefetch; stage A issued before GEMM1,
// stage B before the barrier.
// ===========================================================================
#define HPAD2 520

__global__ __launch_bounds__(512, 4) void k_hy4(
    const f16* __restrict__ slots16, const f16* __restrict__ w1T,
    const float* __restrict__ b1, const f16* __restrict__ w2T,
    const float* __restrict__ b2, const int* __restrict__ action,
    const int* __restrict__ order, f16* __restrict__ yT16)
{
  __shared__ f16 hs[32][HPAD2];
  const int bx = blockIdx.x;
  const int L  = (bx & 7) * 64 + (bx >> 3);   // bijective, 512 % 8 == 0
  const int e = L >> 7, sb = (L >> 1) & 63, half = L & 1;
  const int b = order[sb];
  const int s0 = half * 32;
  int a = action[b];
  a = (a < 0) ? 0 : (a >= A_ ? A_ - 1 : a);
  const long z = (long)b * 4 + e;

  const int t = threadIdx.x, w = t >> 6, lane = t & 63;
  const int lr = lane & 15, lk = (lane >> 4) * 8;
  const int orow = (lane >> 4) * 4;

  // GEMM2 B base (wave w covers y-cols w*32 .. w*32+31), K-contiguous f16
  const int n0_2 = w * 32;
  const f16* Bp2 = w2T + (long)e * ((long)K2_ * H_)
                 + ((long)a * D_ + n0_2 + lr) * H_ + lk;

  // stage-A prefetch (k = 0..31) issued before GEMM1
  f16x8 bA0 = *reinterpret_cast<const f16x8*>(Bp2);
  f16x8 bA1 = *reinterpret_cast<const f16x8*>(Bp2 + 16 * H_);

  // ---- GEMM1: h[32][512] = relu(slots[32x256] @ w1T[e]^T + b1) ------------
  {
    const int n0 = w * 64;
    f32x4 acc[2][4] = {};
    const f16* Ap = slots16 + z * (S_ * D_) + (long)(s0 + lr) * D_ + lk;
    const f16* Bp = w1T + (long)e * (H_ * D_) + (long)(n0 + lr) * D_ + lk;

    f16x8 afc[2], bfc[4], afn[2], bfn[4];
#pragma unroll
    for (int fi = 0; fi < 2; ++fi)
      afc[fi] = *reinterpret_cast<const f16x8*>(Ap + (long)fi * 16 * D_);
#pragma unroll
    for (int fj = 0; fj < 4; ++fj)
      bfc[fj] = *reinterpret_cast<const f16x8*>(Bp + (long)fj * 16 * D_);

#pragma unroll
    for (int it = 0; it < 8; ++it) {
      const int k1 = (it + 1) * 32;
      if (it < 7) {
#pragma unroll
        for (int fi = 0; fi < 2; ++fi)
          afn[fi] = *reinterpret_cast<const f16x8*>(Ap + (long)fi * 16 * D_ + k1);
#pragma unroll
        for (int fj = 0; fj < 4; ++fj)
          bfn[fj] = *reinterpret_cast<const f16x8*>(Bp + (long)fj * 16 * D_ + k1);
      }
#pragma unroll
      for (int fi = 0; fi < 2; ++fi)
#pragma unroll
        for (int fj = 0; fj < 4; ++fj)
          acc[fi][fj] = __builtin_amdgcn_mfma_f32_16x16x32_f16(
              afc[fi], bfc[fj], acc[fi][fj], 0, 0, 0);
#pragma unroll
      for (int q = 0; q < 2; ++q) afc[q] = afn[q];
#pragma unroll
      for (int q = 0; q < 4; ++q) bfc[q] = bfn[q];
    }
#pragma unroll
    for (int fi = 0; fi < 2; ++fi)
#pragma unroll
      for (int fj = 0; fj < 4; ++fj) {
        const int gm = fi * 16 + orow;
        const int gn = n0 + fj * 16 + lr;
        const float bv = b1[e * H_ + gn];
#pragma unroll
        for (int r = 0; r < 4; ++r)
          hs[gm + r][gn] = (f16)fmaxf(acc[fi][fj][r] + bv, 0.f);
      }
  }

  // stage-B prefetch (k = 32..63) issued before the barrier
  f16x8 bB0 = *reinterpret_cast<const f16x8*>(Bp2 + 32);
  f16x8 bB1 = *reinterpret_cast<const f16x8*>(Bp2 + 16 * H_ + 32);

  __syncthreads();

  // ---- GEMM2: y[32 s][32 d per wave] = h @ w2T[a-slice]^T + b2 ------------
  {
    f32x4 acc[2][2] = {};
#pragma unroll
    for (int it = 0; it < 16; ++it) {
      const int k0 = it * 32;
      f16x8 b0, b1f;
      if ((it & 1) == 0) {
        b0 = bA0; b1f = bA1;
        if (it + 2 < 16) {
          bA0 = *reinterpret_cast<const f16x8*>(Bp2 + k0 + 64);
          bA1 = *reinterpret_cast<const f16x8*>(Bp2 + 16 * H_ + k0 + 64);
        }
      } else {
        b0 = bB0; b1f = bB1;
        if (it + 2 < 16) {
          bB0 = *reinterpret_cast<const f16x8*>(Bp2 + k0 + 64);
          bB1 = *reinterpret_cast<const f16x8*>(Bp2 + 16 * H_ + k0 + 64);
        }
      }
      f16x8 af[2];
#pragma unroll
      for (int fi = 0; fi < 2; ++fi)
        af[fi] = *reinterpret_cast<const f16x8*>(&hs[fi * 16 + lr][k0 + lk]);
      acc[0][0] = __builtin_amdgcn_mfma_f32_16x16x32_f16(af[0], b0,  acc[0][0], 0, 0, 0);
      acc[0][1] = __builtin_amdgcn_mfma_f32_16x16x32_f16(af[0], b1f, acc[0][1], 0, 0, 0);
      acc[1][0] = __builtin_amdgcn_mfma_f32_16x16x32_f16(af[1], b0,  acc[1][0], 0, 0, 0);
      acc[1][1] = __builtin_amdgcn_mfma_f32_16x16x32_f16(af[1], b1f, acc[1][1], 0, 0, 0);
    }
    // transposed write: yT16[b][d][es = e*64 + s0 + s]
#pragma unroll
    for (int fi = 0; fi < 2; ++fi)
#pragma unroll
      for (int fj = 0; fj < 2; ++fj) {
        const int gm = fi * 16 + orow;           // s within slice
        const int gn = n0_2 + fj * 16 + lr;      // d
        const float bv = b2[e * K2_ + a * D_ + gn];
        f16x4 h4;
#pragma unroll
        for (int r = 0; r < 4; ++r) h4[r] = (f16)(acc[fi][fj][r] + bv);
        *reinterpret_cast<f16x4*>(
            &yT16[(long)b * (D_ * ES_) + (long)gn * ES_ + e * S_ + s0 + gm]) = h4;
      }
  }
}

// ===========================================================================
extern "C" void kernel_launch(void* const* d_in, const int* in_sizes, int n_in,
                              void* d_out, int out_size, void* d_ws, size_t ws_size,
                              hipStream_t stream)
{
  const float* obs    = (const float*)d_in[0];
  const int*   action = (const int*)d_in[1];
  const float* phi    = (const float*)d_in[2];
  const float* w1     = (const float*)d_in[3];
  const float* b1     = (const float*)d_in[4];
  const float* w2     = (const float*)d_in[5];
  const float* b2     = (const float*)d_in[6];
  float*       out    = (float*)d_out;

  // Workspace (f16 units), ~63 MB total
  f16* ws = (f16*)d_ws;
  f16* obsT16  = ws + 0;          //  4,194,304
  f16* phiT    = ws + 4194304;    //     65,536
  f16* w1T     = ws + 4259840;    //    524,288
  f16* w2T     = ws + 4784128;    //  9,437,184
  f16* exp16   = ws + 14221312;   //  4,194,304
  f16* expT16  = ws + 18415616;   //  4,194,304
  f16* slots16 = ws + 22609920;   //  4,194,304
  f16* yT16    = ws + 26804224;   //  4,194,304
  float* rowpart = (float*)(ws + 30998528);   // 65,536 f32
  float* colpart = (float*)(ws + 31129600);   // 65,536 f32
  int*   order   = (int*)(ws + 31260672);     // 64 ints

  // --- prep ---
  k_sched   <<<dim3(1),        64,  0, stream>>>(action, order);
  k_cvt_obsT<<<dim3(4, 4, 64), 256, 0, stream>>>(obs, obsT16);
  k_tcvt    <<<dim3(4, 4, 1),  256, 0, stream>>>(phi, phiT, 256, 256, 0, 0);
  k_tcvt    <<<dim3(8, 4, 4),  256, 0, stream>>>(w1, w1T, D_, H_,
                                                 (long)D_ * H_, (long)H_ * D_);
  k_tcvt    <<<dim3(72, 8, 4), 256, 0, stream>>>(w2, w2T, H_, K2_,
                                                 (long)H_ * K2_, (long)K2_ * H_);
  // --- pipeline ---
  k_logits_f<<<dim3(4, 4, 64), 256, 0, stream>>>(obs, phiT, exp16, expT16,
                                                 rowpart, colpart);
  k_slots_s <<<dim3(4, 4, 64), 256, 0, stream>>>(expT16, obsT16, colpart, slots16);
  k_hy4     <<<dim3(512),      512, 0, stream>>>(slots16, w1T, b1, w2T, b2,
                                                 action, order, yT16);
  k_out_s   <<<dim3(4, 4, 64), 256, 0, stream>>>(exp16, yT16, rowpart, out);
}

// Round 11
// 112.009 us; speedup vs baseline: 1.1821x; 1.1821x over previous
//
#include <hip/hip_runtime.h>

// Problem constants
#define B_   64
#define M_   256
#define D_   256
#define A_   18
#define E_   4
#define S_   64
#define ES_  256          // E_*S_ == M_
#define H_   512
#define K2_  (A_*D_)      // 4608

typedef _Float16 f16;
typedef _Float16 f16x4 __attribute__((ext_vector_type(4)));
typedef _Float16 f16x8 __attribute__((ext_vector_type(8)));
typedef float    f32x4 __attribute__((ext_vector_type(4)));

static __device__ __forceinline__ f16x8 cat8(f16x4 a, f16x4 b) {
  return __builtin_shufflevector(a, b, 0, 1, 2, 3, 4, 5, 6, 7);
}
static __device__ __forceinline__ f16x8 pack8(float4 u0, float4 u1) {
  f16x8 a;
  a[0] = (f16)u0.x; a[1] = (f16)u0.y; a[2] = (f16)u0.z; a[3] = (f16)u0.w;
  a[4] = (f16)u1.x; a[5] = (f16)u1.y; a[6] = (f16)u1.z; a[7] = (f16)u1.w;
  return a;
}

// ===========================================================================
// k_prep: ONE launch doing all prep concurrently, branch on block range:
//   [0,1024)     obs fp32 [b][M][D] -> obsT16 [b][D][M]
//   [1024,1040)  phi -> phiT  (256x256 transpose+cvt)
//   [1040,1168)  w1  -> w1T   (per-e 256x512 -> 512x256)
//   [1168,3472)  w2  -> w2T   (per-e 512x4608 -> 4608x512)
//   [3472]       action rank-sort -> order
// ===========================================================================
__global__ __launch_bounds__(256) void k_prep(
    const float* __restrict__ obs, const float* __restrict__ phi,
    const float* __restrict__ w1, const float* __restrict__ w2,
    const int* __restrict__ action,
    f16* __restrict__ obsT16, f16* __restrict__ phiT,
    f16* __restrict__ w1T, f16* __restrict__ w2T, int* __restrict__ order)
{
  __shared__ f16 T[64][68];
  const int bx = blockIdx.x;
  const int t  = threadIdx.x;
  const int rr = t >> 4, cc = (t & 15) * 4;

  const float* src; f16* dst; int R, C, r0, c0;
  if (bx < 1024) {
    const int x = bx & 3, y = (bx >> 2) & 3, z = bx >> 4;
    src = obs + (long)z * (M_ * D_); dst = obsT16 + (long)z * (M_ * D_);
    R = M_; C = D_; r0 = y * 64; c0 = x * 64;
  } else if (bx < 1040) {
    const int idx = bx - 1024;
    src = phi; dst = phiT;
    R = D_; C = ES_; r0 = (idx >> 2) * 64; c0 = (idx & 3) * 64;
  } else if (bx < 1168) {
    const int idx = bx - 1040;
    const int x = idx & 7, y = (idx >> 3) & 3, z = idx >> 5;
    src = w1 + (long)z * (D_ * H_); dst = w1T + (long)z * (H_ * D_);
    R = D_; C = H_; r0 = y * 64; c0 = x * 64;
  } else if (bx < 3472) {
    const int idx = bx - 1168;
    const int x = idx % 72, rem = idx / 72, y = rem & 7, z = rem >> 3;
    src = w2 + (long)z * ((long)H_ * K2_); dst = w2T + (long)z * ((long)K2_ * H_);
    R = H_; C = K2_; r0 = y * 64; c0 = x * 64;
  } else {
    if (t < B_) {
      const int a = action[t];
      int rank = 0;
#pragma unroll 8
      for (int i = 0; i < B_; ++i) {
        const int ai = action[i];
        rank += (ai < a) || (ai == a && i < t);
      }
      order[rank] = t;
    }
    return;
  }

  // transpose+convert 64x64 tile: dst[c][r] = (f16)src[r][c]
#pragma unroll
  for (int p = 0; p < 4; ++p) {
    const int row = rr + p * 16;
    const float4 v = *reinterpret_cast<const float4*>(
        &src[(long)(r0 + row) * C + c0 + cc]);
    T[row][cc + 0] = (f16)v.x; T[row][cc + 1] = (f16)v.y;
    T[row][cc + 2] = (f16)v.z; T[row][cc + 3] = (f16)v.w;
  }
  __syncthreads();
#pragma unroll
  for (int p = 0; p < 4; ++p) {
    const int oc = rr + p * 16;
    f16x4 g;
#pragma unroll
    for (int i = 0; i < 4; ++i) g[i] = T[cc + i][oc];
    *reinterpret_cast<f16x4*>(&dst[(long)(c0 + oc) * R + r0 + cc]) = g;
  }
}

// ===========================================================================
// k_logits_f: per 64x64 tile of logits[b] = obs_fp32[b] @ phiT^T:
//   exp16 [b][m][es], expT16[b][es][m], rowpart/colpart partial sums.
// grid (4 es, 4 m, 64 b), 256 threads
// ===========================================================================
__global__ __launch_bounds__(256) void k_logits_f(
    const float* __restrict__ obs, const f16* __restrict__ phiT,
    f16* __restrict__ exp16, f16* __restrict__ expT16,
    float* __restrict__ rowpart, float* __restrict__ colpart)
{
  __shared__ f16 T[64][68];
  const int t = threadIdx.x;
  const int es0 = blockIdx.x * 64, m0g = blockIdx.y * 64;
  const int bz = blockIdx.z;
  const long bo = (long)bz * (M_ * D_);
  const long bb = (long)bz * (M_ * ES_);

  const int w = t >> 6, lane = t & 63;
  const int wr = w >> 1, wc = w & 1;
  const int lr = lane & 15, lk = (lane >> 4) * 8;
  const int orow = (lane >> 4) * 4;

  f32x4 acc[2][2] = {};
  const float* Ap = obs + bo + (long)(m0g + wr * 32 + lr) * D_ + lk;
  const f16*   Bp = phiT + (long)(es0 + wc * 32 + lr) * D_ + lk;
#pragma unroll
  for (int k0 = 0; k0 < D_; k0 += 32) {
    const float4 u00 = *reinterpret_cast<const float4*>(Ap + k0);
    const float4 u01 = *reinterpret_cast<const float4*>(Ap + k0 + 4);
    const float4 u10 = *reinterpret_cast<const float4*>(Ap + 16 * D_ + k0);
    const float4 u11 = *reinterpret_cast<const float4*>(Ap + 16 * D_ + k0 + 4);
    const f16x8 a0 = pack8(u00, u01);
    const f16x8 a1 = pack8(u10, u11);
    const f16x8 b0 = *reinterpret_cast<const f16x8*>(Bp + k0);
    const f16x8 b1 = *reinterpret_cast<const f16x8*>(Bp + 16 * D_ + k0);
    acc[0][0] = __builtin_amdgcn_mfma_f32_16x16x32_f16(a0, b0, acc[0][0], 0, 0, 0);
    acc[0][1] = __builtin_amdgcn_mfma_f32_16x16x32_f16(a0, b1, acc[0][1], 0, 0, 0);
    acc[1][0] = __builtin_amdgcn_mfma_f32_16x16x32_f16(a1, b0, acc[1][0], 0, 0, 0);
    acc[1][1] = __builtin_amdgcn_mfma_f32_16x16x32_f16(a1, b1, acc[1][1], 0, 0, 0);
  }
#pragma unroll
  for (int fi = 0; fi < 2; ++fi)
#pragma unroll
    for (int fj = 0; fj < 2; ++fj) {
      const int gm = wr * 32 + fi * 16 + orow;
      const int gn = wc * 32 + fj * 16 + lr;
#pragma unroll
      for (int r = 0; r < 4; ++r)
        T[gm + r][gn] = (f16)__expf(acc[fi][fj][r]);
    }
  __syncthreads();

  {  // exp16 [m][es]
    const int row = t >> 2, q = t & 3;
    f16x4 p0 = *reinterpret_cast<const f16x4*>(&T[row][q * 16 + 0]);
    f16x4 p1 = *reinterpret_cast<const f16x4*>(&T[row][q * 16 + 4]);
    f16x4 p2 = *reinterpret_cast<const f16x4*>(&T[row][q * 16 + 8]);
    f16x4 p3 = *reinterpret_cast<const f16x4*>(&T[row][q * 16 + 12]);
    f16* dst = exp16 + bb + (long)(m0g + row) * ES_ + es0 + q * 16;
    *reinterpret_cast<f16x8*>(dst)     = cat8(p0, p1);
    *reinterpret_cast<f16x8*>(dst + 8) = cat8(p2, p3);
  }
  {  // expT16 [es][m]
    const int er = t >> 2, q = t & 3;
    f16x4 g[4];
#pragma unroll
    for (int j = 0; j < 4; ++j)
#pragma unroll
      for (int i = 0; i < 4; ++i)
        g[j][i] = T[q * 16 + j * 4 + i][er];
    f16* dst = expT16 + bb + (long)(es0 + er) * M_ + m0g + q * 16;
    *reinterpret_cast<f16x8*>(dst)     = cat8(g[0], g[1]);
    *reinterpret_cast<f16x8*>(dst + 8) = cat8(g[2], g[3]);
  }
  if (t < 64) {
    float s = 0.f;
#pragma unroll
    for (int i = 0; i < 16; ++i) {
      const f16x4 v = *reinterpret_cast<const f16x4*>(&T[t][i * 4]);
      s += (float)v[0] + (float)v[1] + (float)v[2] + (float)v[3];
    }
    rowpart[((long)bz * 256 + m0g + t) * 4 + blockIdx.x] = s;
  } else if (t < 128) {
    const int es = t - 64;
    float s = 0.f;
#pragma unroll
    for (int i = 0; i < 64; ++i) s += (float)T[i][es];
    colpart[((long)bz * 256 + es0 + es) * 4 + blockIdx.y] = s;
  }
}

// ===========================================================================
// k_out_s: out[b][m][d] (fp32) = (1/rowsum[m]) * exp16[b] @ yT16[b]^T
// grid (4 d, 4 m, 64 b), 256 threads
// ===========================================================================
__global__ __launch_bounds__(256) void k_out_s(
    const f16* __restrict__ exp16, const f16* __restrict__ yT16,
    const float* __restrict__ rowpart, float* __restrict__ out)
{
  const int t = threadIdx.x;
  const int w = t >> 6, lane = t & 63;
  const int wr = w >> 1, wc = w & 1;
  const int m0 = blockIdx.y * 64 + wr * 32;
  const int n0 = blockIdx.x * 64 + wc * 32;
  const int lr = lane & 15, lk = (lane >> 4) * 8;
  const long b = blockIdx.z;

  f32x4 acc[2][2] = {};
  const f16* Ap = exp16 + b * (M_ * ES_) + (long)(m0 + lr) * ES_ + lk;
  const f16* Bp = yT16 + b * (D_ * ES_) + (long)(n0 + lr) * ES_ + lk;
#pragma unroll
  for (int k0 = 0; k0 < ES_; k0 += 32) {
    const f16x8 a0 = *reinterpret_cast<const f16x8*>(Ap + k0);
    const f16x8 a1 = *reinterpret_cast<const f16x8*>(Ap + 16 * ES_ + k0);
    const f16x8 b0 = *reinterpret_cast<const f16x8*>(Bp + k0);
    const f16x8 b1 = *reinterpret_cast<const f16x8*>(Bp + 16 * ES_ + k0);
    acc[0][0] = __builtin_amdgcn_mfma_f32_16x16x32_f16(a0, b0, acc[0][0], 0, 0, 0);
    acc[0][1] = __builtin_amdgcn_mfma_f32_16x16x32_f16(a0, b1, acc[0][1], 0, 0, 0);
    acc[1][0] = __builtin_amdgcn_mfma_f32_16x16x32_f16(a1, b0, acc[1][0], 0, 0, 0);
    acc[1][1] = __builtin_amdgcn_mfma_f32_16x16x32_f16(a1, b1, acc[1][1], 0, 0, 0);
  }

  const int orow = (lane >> 4) * 4;
  float* C = out + b * (M_ * D_);
#pragma unroll
  for (int fi = 0; fi < 2; ++fi) {
    float inv[4];
#pragma unroll
    for (int r = 0; r < 4; ++r) {
      const int gm = m0 + fi * 16 + orow + r;
      const float4 rp = *reinterpret_cast<const float4*>(&rowpart[((long)b * 256 + gm) * 4]);
      inv[r] = 1.0f / (rp.x + rp.y + rp.z + rp.w);
    }
#pragma unroll
    for (int fj = 0; fj < 2; ++fj) {
      const int gm = m0 + fi * 16 + orow;
      const int gn = n0 + fj * 16 + lr;
#pragma unroll
      for (int r = 0; r < 4; ++r)
        C[(long)(gm + r) * D_ + gn] = acc[fi][fj][r] * inv[r];
    }
  }
}

// ===========================================================================
// k_hy5: fully-fused slots->h->y per (b,e,half-of-s). 512 blocks, 512 thr.
//  GEMM0: slots[32 es][256 d] = (1/colsum) * expT16 @ obsT16^T  -> LDS ss
//  GEMM1: h[32][512] = relu(ss @ w1T^T + b1)                    -> LDS hs
//  GEMM2: y[32][256] = hs @ w2T[a-slice]^T + b2  -> yT16 (transposed write)
// Block decode: XCD-chunk swizzle -> {e major, action-sorted b, half minor}
// so blocks sharing the (e,action) w2T slice run adjacently on one XCD.
// ===========================================================================
#define SPAD 264   // 256 + 8
#define HPAD2 520  // 512 + 8

__global__ __launch_bounds__(512, 4) void k_hy5(
    const f16* __restrict__ expT16, const f16* __restrict__ obsT16,
    const float* __restrict__ colpart,
    const f16* __restrict__ w1T, const float* __restrict__ b1,
    const f16* __restrict__ w2T, const float* __restrict__ b2,
    const int* __restrict__ action, const int* __restrict__ order,
    f16* __restrict__ yT16)
{
  __shared__ f16 ss[32][SPAD];
  __shared__ f16 hs[32][HPAD2];
  const int bx = blockIdx.x;
  const int L  = (bx & 7) * 64 + (bx >> 3);   // bijective, 512 % 8 == 0
  const int e = L >> 7, sb = (L >> 1) & 63, half = L & 1;
  const int b = order[sb];
  const int s0 = half * 32;
  int a = action[b];
  a = (a < 0) ? 0 : (a >= A_ ? A_ - 1 : a);

  const int t = threadIdx.x, w = t >> 6, lane = t & 63;
  const int lr = lane & 15, lk = (lane >> 4) * 8;
  const int orow = (lane >> 4) * 4;

  // GEMM2 B base (wave w covers y-cols w*32..w*32+31), K-contiguous f16;
  // stage-A prefetch issued at kernel start to maximize hiding.
  const int n0_2 = w * 32;
  const f16* Bp2 = w2T + (long)e * ((long)K2_ * H_)
                 + ((long)a * D_ + n0_2 + lr) * H_ + lk;
  f16x8 bA0 = *reinterpret_cast<const f16x8*>(Bp2);
  f16x8 bA1 = *reinterpret_cast<const f16x8*>(Bp2 + 16 * H_);

  // ---- GEMM0: slots tile -> ss (scaled by 1/colsum) -----------------------
  {
    const int n0 = w * 32;                 // d cols per wave
    f32x4 acc[2][2] = {};
    const f16* Ap = expT16 + (long)b * (ES_ * M_)
                  + (long)(e * S_ + s0 + lr) * M_ + lk;
    const f16* Bp = obsT16 + (long)b * (D_ * M_) + (long)(n0 + lr) * M_ + lk;
#pragma unroll
    for (int k0 = 0; k0 < M_; k0 += 32) {
      const f16x8 a0 = *reinterpret_cast<const f16x8*>(Ap + k0);
      const f16x8 a1 = *reinterpret_cast<const f16x8*>(Ap + 16 * M_ + k0);
      const f16x8 b0 = *reinterpret_cast<const f16x8*>(Bp + k0);
      const f16x8 b1 = *reinterpret_cast<const f16x8*>(Bp + 16 * M_ + k0);
      acc[0][0] = __builtin_amdgcn_mfma_f32_16x16x32_f16(a0, b0, acc[0][0], 0, 0, 0);
      acc[0][1] = __builtin_amdgcn_mfma_f32_16x16x32_f16(a0, b1, acc[0][1], 0, 0, 0);
      acc[1][0] = __builtin_amdgcn_mfma_f32_16x16x32_f16(a1, b0, acc[1][0], 0, 0, 0);
      acc[1][1] = __builtin_amdgcn_mfma_f32_16x16x32_f16(a1, b1, acc[1][1], 0, 0, 0);
    }
#pragma unroll
    for (int fi = 0; fi < 2; ++fi) {
      float inv[4];
#pragma unroll
      for (int r = 0; r < 4; ++r) {
        const int ges = e * S_ + s0 + fi * 16 + orow + r;
        const float4 cp = *reinterpret_cast<const float4*>(
            &colpart[((long)b * 256 + ges) * 4]);
        inv[r] = 1.0f / (cp.x + cp.y + cp.z + cp.w);
      }
#pragma unroll
      for (int fj = 0; fj < 2; ++fj) {
        const int gm = fi * 16 + orow;
        const int gn = n0 + fj * 16 + lr;
#pragma unroll
        for (int r = 0; r < 4; ++r)
          ss[gm + r][gn] = (f16)(acc[fi][fj][r] * inv[r]);
      }
    }
  }
  __syncthreads();

  // ---- GEMM1: h[32][512] = relu(ss @ w1T[e]^T + b1) -> hs -----------------
  {
    const int n0 = w * 64;
    f32x4 acc[2][4] = {};
    const f16* Bp = w1T + (long)e * (H_ * D_) + (long)(n0 + lr) * D_ + lk;
#pragma unroll
    for (int it = 0; it < 8; ++it) {
      const int k0 = it * 32;
      f16x8 af[2], bf[4];
#pragma unroll
      for (int fi = 0; fi < 2; ++fi)
        af[fi] = *reinterpret_cast<const f16x8*>(&ss[fi * 16 + lr][k0 + lk]);
#pragma unroll
      for (int fj = 0; fj < 4; ++fj)
        bf[fj] = *reinterpret_cast<const f16x8*>(Bp + (long)fj * 16 * D_ + k0);
#pragma unroll
      for (int fi = 0; fi < 2; ++fi)
#pragma unroll
        for (int fj = 0; fj < 4; ++fj)
          acc[fi][fj] = __builtin_amdgcn_mfma_f32_16x16x32_f16(
              af[fi], bf[fj], acc[fi][fj], 0, 0, 0);
    }
#pragma unroll
    for (int fi = 0; fi < 2; ++fi)
#pragma unroll
      for (int fj = 0; fj < 4; ++fj) {
        const int gm = fi * 16 + orow;
        const int gn = n0 + fj * 16 + lr;
        const float bv = b1[e * H_ + gn];
#pragma unroll
        for (int r = 0; r < 4; ++r)
          hs[gm + r][gn] = (f16)fmaxf(acc[fi][fj][r] + bv, 0.f);
      }
  }

  // stage-B prefetch (k = 32..63) issued before the barrier
  f16x8 bB0 = *reinterpret_cast<const f16x8*>(Bp2 + 32);
  f16x8 bB1 = *reinterpret_cast<const f16x8*>(Bp2 + 16 * H_ + 32);

  __syncthreads();

  // ---- GEMM2: y[32 s][32 d per wave] = hs @ w2T[a-slice]^T + b2 -----------
  {
    f32x4 acc[2][2] = {};
#pragma unroll
    for (int it = 0; it < 16; ++it) {
      const int k0 = it * 32;
      f16x8 b0, b1f;
      if ((it & 1) == 0) {
        b0 = bA0; b1f = bA1;
        if (it + 2 < 16) {
          bA0 = *reinterpret_cast<const f16x8*>(Bp2 + k0 + 64);
          bA1 = *reinterpret_cast<const f16x8*>(Bp2 + 16 * H_ + k0 + 64);
        }
      } else {
        b0 = bB0; b1f = bB1;
        if (it + 2 < 16) {
          bB0 = *reinterpret_cast<const f16x8*>(Bp2 + k0 + 64);
          bB1 = *reinterpret_cast<const f16x8*>(Bp2 + 16 * H_ + k0 + 64);
        }
      }
      f16x8 af[2];
#pragma unroll
      for (int fi = 0; fi < 2; ++fi)
        af[fi] = *reinterpret_cast<const f16x8*>(&hs[fi * 16 + lr][k0 + lk]);
      acc[0][0] = __builtin_amdgcn_mfma_f32_16x16x32_f16(af[0], b0,  acc[0][0], 0, 0, 0);
      acc[0][1] = __builtin_amdgcn_mfma_f32_16x16x32_f16(af[0], b1f, acc[0][1], 0, 0, 0);
      acc[1][0] = __builtin_amdgcn_mfma_f32_16x16x32_f16(af[1], b0,  acc[1][0], 0, 0, 0);
      acc[1][1] = __builtin_amdgcn_mfma_f32_16x16x32_f16(af[1], b1f, acc[1][1], 0, 0, 0);
    }
    // transposed write: yT16[b][d][es = e*64 + s0 + s]
#pragma unroll
    for (int fi = 0; fi < 2; ++fi)
#pragma unroll
      for (int fj = 0; fj < 2; ++fj) {
        const int gm = fi * 16 + orow;           // s within slice
        const int gn = n0_2 + fj * 16 + lr;      // d
        const float bv = b2[e * K2_ + a * D_ + gn];
        f16x4 h4;
#pragma unroll
        for (int r = 0; r < 4; ++r) h4[r] = (f16)(acc[fi][fj][r] + bv);
        *reinterpret_cast<f16x4*>(
            &yT16[(long)b * (D_ * ES_) + (long)gn * ES_ + e * S_ + s0 + gm]) = h4;
      }
  }
}

// ===========================================================================
extern "C" void kernel_launch(void* const* d_in, const int* in_sizes, int n_in,
                              void* d_out, int out_size, void* d_ws, size_t ws_size,
                              hipStream_t stream)
{
  const float* obs    = (const float*)d_in[0];
  const int*   action = (const int*)d_in[1];
  const float* phi    = (const float*)d_in[2];
  const float* w1     = (const float*)d_in[3];
  const float* w2     = (const float*)d_in[5];
  const float* b1     = (const float*)d_in[4];
  const float* b2     = (const float*)d_in[6];
  float*       out    = (float*)d_out;

  // Workspace (f16 units), ~55 MB total
  f16* ws = (f16*)d_ws;
  f16* obsT16  = ws + 0;          //  4,194,304
  f16* phiT    = ws + 4194304;    //     65,536
  f16* w1T     = ws + 4259840;    //    524,288
  f16* w2T     = ws + 4784128;    //  9,437,184
  f16* exp16   = ws + 14221312;   //  4,194,304
  f16* expT16  = ws + 18415616;   //  4,194,304
  f16* yT16    = ws + 22609920;   //  4,194,304
  float* rowpart = (float*)(ws + 26804224);   // 65,536 f32
  float* colpart = (float*)(ws + 26935296);   // 65,536 f32
  int*   order   = (int*)(ws + 27066368);     // 64 ints

  k_prep    <<<dim3(3473),     256, 0, stream>>>(obs, phi, w1, w2, action,
                                                 obsT16, phiT, w1T, w2T, order);
  k_logits_f<<<dim3(4, 4, 64), 256, 0, stream>>>(obs, phiT, exp16, expT16,
                                                 rowpart, colpart);
  k_hy5     <<<dim3(512),      512, 0, stream>>>(expT16, obsT16, colpart,
                                                 w1T, b1, w2T, b2,
                                                 action, order, yT16);
  k_out_s   <<<dim3(4, 4, 64), 256, 0, stream>>>(exp16, yT16, rowpart, out);
}